// Round 1
// baseline (504.776 us; speedup 1.0000x reference)
//
#include <hip/hip_runtime.h>

#define HIDDEN  128
#define REDUCED 64
#define NGRAPHS 4096

// ---------------------------------------------------------------------------
// Kernel 1: segment-sum pool. batch is SORTED, so graph g's nodes form a
// contiguous range found by binary search. One block (128 thr) per graph.
// Thread t: row-slot r = t>>5 (4 rows in flight), col c = t&31 (float4 of
// features). No atomics; every pooled element is written (empty segs -> 0),
// so no workspace zero-init needed despite 0xAA poison.
// ---------------------------------------------------------------------------
__global__ void pool_kernel(const float* __restrict__ x,
                            const int* __restrict__ batch,
                            float* __restrict__ pooled, int n_nodes) {
    const int g = blockIdx.x;
    const int t = threadIdx.x;
    __shared__ int s_range[2];
    if (t < 2) {
        int lo = 0, hi = n_nodes;
        if (t == 0) {
            while (lo < hi) { int mid = (lo + hi) >> 1; if (batch[mid] <  g) lo = mid + 1; else hi = mid; }
        } else {
            while (lo < hi) { int mid = (lo + hi) >> 1; if (batch[mid] <= g) lo = mid + 1; else hi = mid; }
        }
        s_range[t] = lo;
    }
    __syncthreads();
    const int lo = s_range[0], hi = s_range[1];
    const int r = t >> 5, c = t & 31;

    float4 acc = make_float4(0.f, 0.f, 0.f, 0.f);
    for (int n = lo + r; n < hi; n += 4) {
        const float4 v = ((const float4*)(x + (size_t)n * HIDDEN))[c];
        acc.x += v.x; acc.y += v.y; acc.z += v.z; acc.w += v.w;
    }
    __shared__ float4 red[4][32];
    red[r][c] = acc;
    __syncthreads();
    if (r == 0) {
        const float4 a = red[0][c], b = red[1][c], d = red[2][c], e = red[3][c];
        float4 s;
        s.x = a.x + b.x + d.x + e.x;
        s.y = a.y + b.y + d.y + e.y;
        s.z = a.z + b.z + d.z + e.z;
        s.w = a.w + b.w + d.w + e.w;
        ((float4*)(pooled + (size_t)g * HIDDEN))[c] = s;
    }
}

// ---------------------------------------------------------------------------
// Kernel 2: per-graph squeeze-excite MLP. One 128-thread block per graph.
// h = relu(pooled @ W1 + b1)  [64];  y = sigmoid(h @ W2 + b2)  [128].
// W1[i*64+j] / W2[j*128+k] reads are coalesced across threads; 64 KB of
// weights stays L2-resident across the 4096 blocks.
// ---------------------------------------------------------------------------
__global__ void mlp_kernel(const float* __restrict__ pooled,
                           const float* __restrict__ W1, const float* __restrict__ b1,
                           const float* __restrict__ W2, const float* __restrict__ b2,
                           float* __restrict__ y) {
    const int g = blockIdx.x;
    const int t = threadIdx.x;  // 128
    __shared__ float p_s[HIDDEN];
    __shared__ float h_s[REDUCED];
    p_s[t] = pooled[(size_t)g * HIDDEN + t];
    __syncthreads();
    if (t < REDUCED) {
        float acc = b1[t];
        #pragma unroll 8
        for (int i = 0; i < HIDDEN; ++i) acc = fmaf(p_s[i], W1[i * REDUCED + t], acc);
        h_s[t] = acc > 0.f ? acc : 0.f;
    }
    __syncthreads();
    float acc = b2[t];
    #pragma unroll 8
    for (int j = 0; j < REDUCED; ++j) acc = fmaf(h_s[j], W2[j * HIDDEN + t], acc);
    y[(size_t)g * HIDDEN + t] = 1.f / (1.f + __expf(-acc));
}

// ---------------------------------------------------------------------------
// Kernel 3: out[n] = x[n] * y[batch[n]] — pure-bandwidth float4 elementwise.
// 32 consecutive threads share one node -> batch[n] load broadcasts; y row
// (2 MB table) stays L2-resident.
// ---------------------------------------------------------------------------
__global__ void modulate_kernel(const float* __restrict__ x,
                                const int* __restrict__ batch,
                                const float* __restrict__ y,
                                float* __restrict__ out, long long total4) {
    const long long idx = (long long)blockIdx.x * blockDim.x + threadIdx.x;
    if (idx >= total4) return;
    const long long n = idx >> 5;   // node
    const int c = (int)(idx & 31);  // float4 column
    const int g = batch[n];
    const float4 xv = ((const float4*)x)[idx];
    const float4 yv = ((const float4*)y)[(size_t)g * (HIDDEN / 4) + c];
    float4 o;
    o.x = xv.x * yv.x; o.y = xv.y * yv.y; o.z = xv.z * yv.z; o.w = xv.w * yv.w;
    ((float4*)out)[idx] = o;
}

extern "C" void kernel_launch(void* const* d_in, const int* in_sizes, int n_in,
                              void* d_out, int out_size, void* d_ws, size_t ws_size,
                              hipStream_t stream) {
    const float* x     = (const float*)d_in[0];
    const int*   batch = (const int*)d_in[1];
    // d_in[2] is the scalar `size` (4096) — fixed-shape problem, hardcoded.
    const float* W1 = (const float*)d_in[3];
    const float* b1 = (const float*)d_in[4];
    const float* W2 = (const float*)d_in[5];
    const float* b2 = (const float*)d_in[6];
    float* out = (float*)d_out;

    const int n_nodes = in_sizes[0] / HIDDEN;

    float* pooled = (float*)d_ws;                       // 4096*128*4 = 2 MB
    float* y      = pooled + (size_t)NGRAPHS * HIDDEN;  // 2 MB

    pool_kernel<<<NGRAPHS, 128, 0, stream>>>(x, batch, pooled, n_nodes);
    mlp_kernel<<<NGRAPHS, 128, 0, stream>>>(pooled, W1, b1, W2, b2, y);

    const long long total4 = (long long)n_nodes * (HIDDEN / 4);
    const int blocks = (int)((total4 + 255) / 256);
    modulate_kernel<<<blocks, 256, 0, stream>>>(x, batch, y, out, total4);
}